// Round 3
// baseline (774.180 us; speedup 1.0000x reference)
//
#include <hip/hip_runtime.h>

#define BB 128
#define SS 1000
#define HH 256
#define H3 768
#define H2 512
#define NCHUNK 8

typedef unsigned short u16;
typedef short short8 __attribute__((ext_vector_type(8)));
typedef float floatx4 __attribute__((ext_vector_type(4)));
typedef u16 ushort4v __attribute__((ext_vector_type(4)));

__device__ __forceinline__ float bf2f(u16 u) {
    union { unsigned int i; float f; } v;
    v.i = ((unsigned int)u) << 16;
    return v.f;
}

__device__ __forceinline__ u16 f2bf(float f) {
    unsigned int x = __float_as_uint(f);
    x += 0x7FFFu + ((x >> 16) & 1u);   // round-to-nearest-even
    return (u16)(x >> 16);
}

// tanh via one v_exp + one v_rcp; exact saturation at +-inf.
__device__ __forceinline__ float fast_tanh(float x) {
    float t = __expf(2.0f * x);
    return 1.0f - 2.0f * __builtin_amdgcn_rcpf(t + 1.0f);
}

__device__ __forceinline__ float sigmoidf(float x) {
    return __builtin_amdgcn_rcpf(1.0f + __expf(-x));
}

// async 16B global -> LDS (dest = wave-uniform base + lane*16)
__device__ __forceinline__ void gl2lds16(const void* src, void* dst) {
    __builtin_amdgcn_global_load_lds(
        (const __attribute__((address_space(1))) unsigned int*)src,
        (__attribute__((address_space(3))) unsigned int*)dst,
        16, 0, 0);
}

// ---------------------------------------------------------------------------
// Pre-convert attn_W [768x768] and dec_W [512x512] f32 -> bf16 in workspace.
// ---------------------------------------------------------------------------
__global__ __launch_bounds__(256) void k_prep(
    const float* __restrict__ aW, const float* __restrict__ dW,
    u16* __restrict__ aWb, u16* __restrict__ dWb)
{
    int idx = (blockIdx.x * 256 + threadIdx.x) * 4;
    const float* src;
    u16* dst;
    if (idx < 589824) { src = aW + idx; dst = aWb + idx; }
    else              { src = dW + (idx - 589824); dst = dWb + (idx - 589824); }
    float4 v = *(const float4*)src;
    ushort4v o = { f2bf(v.x), f2bf(v.y), f2bf(v.z), f2bf(v.w) };
    *(ushort4v*)dst = o;
}

// ---------------------------------------------------------------------------
// embed + GRU cell + hidden out + Wh[b,j] = attn_W[j,512:768]·h_new[b]
// ---------------------------------------------------------------------------
__global__ __launch_bounds__(256) void k_gru(
    const float* __restrict__ dec, const float* __restrict__ h0,
    const float* __restrict__ embW, const float* __restrict__ embb,
    const float* __restrict__ Wih, const float* __restrict__ Whh,
    const float* __restrict__ bih, const float* __restrict__ bhh,
    const float* __restrict__ attnW,
    float* __restrict__ Wh, float* __restrict__ out_hidden)
{
    const int b = blockIdx.x, t = threadIdx.x;
    __shared__ float emb_s[HH], h_s[HH], hn_s[HH];

    const float d0 = dec[b * 2 + 0], d1 = dec[b * 2 + 1];
    emb_s[t] = d0 * embW[t * 2 + 0] + d1 * embW[t * 2 + 1] + embb[t];
    h_s[t] = h0[b * HH + t];
    __syncthreads();

    auto dotrow = [&](const float* Wr, const float* xs) -> float {
        float acc = 0.f;
        const float4* p = (const float4*)Wr;
#pragma unroll 8
        for (int c = 0; c < HH / 4; ++c) {
            float4 w = p[c];
            acc += w.x * xs[c * 4 + 0] + w.y * xs[c * 4 + 1]
                 + w.z * xs[c * 4 + 2] + w.w * xs[c * 4 + 3];
        }
        return acc;
    };

    float gr = dotrow(Wih + (size_t)t * HH, emb_s) + bih[t]
             + dotrow(Whh + (size_t)t * HH, h_s) + bhh[t];
    float r = sigmoidf(gr);

    float gz = dotrow(Wih + (size_t)(HH + t) * HH, emb_s) + bih[HH + t]
             + dotrow(Whh + (size_t)(HH + t) * HH, h_s) + bhh[HH + t];
    float z = sigmoidf(gz);

    float xn = dotrow(Wih + (size_t)(2 * HH + t) * HH, emb_s) + bih[2 * HH + t];
    float hn = dotrow(Whh + (size_t)(2 * HH + t) * HH, h_s) + bhh[2 * HH + t];
    float n = fast_tanh(xn + r * hn);

    float hv = (1.0f - z) * n + z * h_s[t];
    out_hidden[b * HH + t] = hv;
    hn_s[t] = hv;
    __syncthreads();

#pragma unroll
    for (int rr = 0; rr < 3; ++rr) {
        int j = t + rr * HH;
        Wh[b * H3 + j] = dotrow(attnW + (size_t)j * H3 + 2 * HH, hn_s);
    }
}

// ---------------------------------------------------------------------------
// Score GEMM: out[b,s] = sum_j vj[j] * tanh( (A @ Wb^T)[s,j] + addj[b,j] )
// A held full-K in regs; W staged via global_load_lds with XOR swizzle,
// double-buffered in K-halves of each 32-j-row group. Single-buffered
// accumulators + inline epilogue keep the UNIFIED (Arch+Acc) VGPR demand
// ~168 so MINW=3 fits without scratch (scores1); scores2's afrag is half
// the size so MINW=4 fits. Trace VGPR_Count is ArchVGPR only — watch
// WRITE_SIZE for spill evidence, not VGPR_Count.
// grid = (8, B); block = 256 = 4 waves; wave = 2 m-tiles of 16 s-rows.
// ---------------------------------------------------------------------------
template <int KSTEPS, int NTILES, int WSTRIDE, int HALVES, int MINW>
__global__ __launch_bounds__(256, MINW) void k_scores(
    const float* __restrict__ A1, const float* __restrict__ A2,
    const u16* __restrict__ Wb, const float* __restrict__ addj,
    const float* __restrict__ vj, float* __restrict__ out)
{
    constexpr int GPR    = KSTEPS * 4;       // 16B granules per j-row (full K)
    constexpr int KH     = KSTEPS / HALVES;  // k-steps per staged unit
    constexpr int GPH    = GPR / HALVES;     // granules per row per unit
    constexpr int BUFU16 = 32 * GPH * 8;     // u16 per buffer (32 rows)
    constexpr int NINSTR = BUFU16 / 2048;    // global_load_lds per wave per stage
    constexpr int NG     = NTILES / 2;       // groups of 32 j-rows
    constexpr int NU     = NG * HALVES;      // total stage units
    constexpr int NJ     = NTILES * 16;      // total j

    __shared__ u16 smem[2 * BUFU16];
    __shared__ float aj_s[NJ], vj_s[NJ];

    const int b = blockIdx.y, t = threadIdx.x;
    const int wave = t >> 6, lane = t & 63;
    const int q = lane >> 4, c = lane & 15;
    const int swz = c & 7;
    const int s_base = blockIdx.x * 128 + wave * 32;
    const int kb = q * 8;

    // ---- stage unit u = g*HALVES + h into buffer (u&1) -------------------
    auto stage = [&](int u) {
        const int g = u / HALVES, h = u % HALVES;
        const int jbase = g * 32;
        u16* base = smem + (u & 1) * BUFU16;
#pragma unroll
        for (int i = 0; i < NINSTR; ++i) {
            int gl = (wave * NINSTR + i) * 64 + lane;   // granule index in buffer
            int r  = gl / GPH;                          // local j-row 0..31
            int p  = gl % GPH;                          // physical granule in row
            int gg = p ^ (r & 7);                       // logical (source) granule
            const u16* src = Wb + (size_t)(jbase + r) * WSTRIDE
                           + h * (GPH * 8) + gg * 8;
            u16* dst = base + (wave * NINSTR + i) * 512;  // uniform/wave
            gl2lds16(src, dst);
        }
    };
    stage(0);

    // ---- preload addj row + v into LDS -----------------------------------
    for (int i = t; i < NJ; i += 256) {
        aj_s[i] = addj[b * NJ + i];
        vj_s[i] = vj[i];
    }

    // ---- A fragments, full K, in registers -------------------------------
    short8 afrag[2][KSTEPS];
#pragma unroll
    for (int mt = 0; mt < 2; ++mt) {
        int row = s_base + mt * 16 + c;
        if (row > SS - 1) row = SS - 1;            // tail clamp; writes guarded
        const size_t abase = (size_t)(b * SS + row) * HH;
#pragma unroll
        for (int ks = 0; ks < KSTEPS; ++ks) {
            int k = ks * 32 + kb;
            const float* src;
            if constexpr (KSTEPS * 32 <= HH) {
                src = A1 + abase + k;
            } else {
                src = (k < HH) ? (A1 + abase + k) : (A2 + abase + (k - HH));
            }
            float4 u0 = *(const float4*)src;
            float4 u1 = *(const float4*)(src + 4);
            short8 f;
            f[0] = (short)f2bf(u0.x); f[1] = (short)f2bf(u0.y);
            f[2] = (short)f2bf(u0.z); f[3] = (short)f2bf(u0.w);
            f[4] = (short)f2bf(u1.x); f[5] = (short)f2bf(u1.y);
            f[6] = (short)f2bf(u1.z); f[7] = (short)f2bf(u1.w);
            afrag[mt][ks] = f;
        }
    }

    float pout[2][4] = {{0.f, 0.f, 0.f, 0.f}, {0.f, 0.f, 0.f, 0.f}};

    for (int g = 0; g < NG; ++g) {
        floatx4 acc[2][2];                    // [jt][mt], single-buffered
#pragma unroll
        for (int jt = 0; jt < 2; ++jt)
#pragma unroll
            for (int mt = 0; mt < 2; ++mt)
                acc[jt][mt] = (floatx4){0.f, 0.f, 0.f, 0.f};

#pragma unroll
        for (int h = 0; h < HALVES; ++h) {
            const int u = g * HALVES + h;
            __syncthreads();                   // buf[u&1] staged; old reads done
            if (u + 1 < NU) stage(u + 1);

            const u16* base = smem + (u & 1) * BUFU16;

            auto ldsrd = [&](int ks, int jt) -> short8 {
                const int paddr = ((jt * 16 + c) * GPH + ((ks * 4 + q) ^ swz)) * 8;
                return *(const short8*)(base + paddr);
            };

#pragma unroll
            for (int ks = 0; ks < KH; ++ks) {
                short8 wf0 = ldsrd(ks, 0);
                short8 wf1 = ldsrd(ks, 1);
                acc[0][0] = __builtin_amdgcn_mfma_f32_16x16x32_bf16(afrag[0][h * KH + ks], wf0, acc[0][0], 0, 0, 0);
                acc[0][1] = __builtin_amdgcn_mfma_f32_16x16x32_bf16(afrag[1][h * KH + ks], wf0, acc[0][1], 0, 0, 0);
                acc[1][0] = __builtin_amdgcn_mfma_f32_16x16x32_bf16(afrag[0][h * KH + ks], wf1, acc[1][0], 0, 0, 0);
                acc[1][1] = __builtin_amdgcn_mfma_f32_16x16x32_bf16(afrag[1][h * KH + ks], wf1, acc[1][1], 0, 0, 0);
            }
        }

        // inline epilogue (VALU) — the 3rd wave/SIMD now provides the overlap
#pragma unroll
        for (int jt = 0; jt < 2; ++jt) {
            const int j = g * 32 + jt * 16 + c;
            const float aj = aj_s[j];
            const float vv = vj_s[j];
#pragma unroll
            for (int r4 = 0; r4 < 4; ++r4) {
                pout[0][r4] += fast_tanh(acc[jt][0][r4] + aj) * vv;
                pout[1][r4] += fast_tanh(acc[jt][1][r4] + aj) * vv;
            }
        }
    }

    // reduce over the 16 lanes of each quad (the j-columns)
#pragma unroll
    for (int mt = 0; mt < 2; ++mt)
#pragma unroll
        for (int r4 = 0; r4 < 4; ++r4)
#pragma unroll
            for (int off = 1; off < 16; off <<= 1)
                pout[mt][r4] += __shfl_xor(pout[mt][r4], off, 64);

    if (c == 0) {
#pragma unroll
        for (int mt = 0; mt < 2; ++mt) {
            const int srow = s_base + mt * 16 + q * 4;
#pragma unroll
            for (int r4 = 0; r4 < 4; ++r4)
                if (srow + r4 < SS) out[b * SS + srow + r4] = pout[mt][r4];
        }
    }
}

// ---------------------------------------------------------------------------
// Softmax over S per batch row; f32 in, f32 out.
// ---------------------------------------------------------------------------
__global__ __launch_bounds__(256) void k_softmax(
    const float* __restrict__ in, float* __restrict__ outf)
{
    const int b = blockIdx.x, t = threadIdx.x;
    __shared__ float red[4];
    const float* rowp = in + b * SS;

    float m = -1e30f;
    for (int s = t; s < SS; s += 256) m = fmaxf(m, rowp[s]);
#pragma unroll
    for (int off = 32; off >= 1; off >>= 1) m = fmaxf(m, __shfl_xor(m, off, 64));
    if ((t & 63) == 0) red[t >> 6] = m;
    __syncthreads();
    m = fmaxf(fmaxf(red[0], red[1]), fmaxf(red[2], red[3]));

    float sum = 0.f;
    for (int s = t; s < SS; s += 256) sum += __expf(rowp[s] - m);
#pragma unroll
    for (int off = 32; off >= 1; off >>= 1) sum += __shfl_xor(sum, off, 64);
    __syncthreads();
    if ((t & 63) == 0) red[t >> 6] = sum;
    __syncthreads();
    sum = red[0] + red[1] + red[2] + red[3];

    const float inv = 1.0f / sum;
    for (int s = t; s < SS; s += 256)
        outf[b * SS + s] = __expf(rowp[s] - m) * inv;
}

// ---------------------------------------------------------------------------
// Context partials: chunk of 125 s-rows per block; wave-per-row float4 loads.
// part[chunk][b][h] = sum_{s in chunk} attn[b,s] * static[b,s,h]
// grid = (NCHUNK, B), 256 threads.
// ---------------------------------------------------------------------------
__global__ __launch_bounds__(256) void k_ctx_part(
    const float* __restrict__ attn, const float* __restrict__ stat,
    float* __restrict__ part)
{
    constexpr int CH = SS / NCHUNK;            // 125
    const int chunk = blockIdx.x, b = blockIdx.y, t = threadIdx.x;
    const int wave = t >> 6, lane = t & 63;

    __shared__ float attn_s[CH];
    __shared__ float red[4][HH];

    for (int i = t; i < CH; i += 256) attn_s[i] = attn[b * SS + chunk * CH + i];
    __syncthreads();

    float4 acc = {0.f, 0.f, 0.f, 0.f};
    const float* base = stat + ((size_t)(b * SS + chunk * CH) * HH) + lane * 4;
#pragma unroll 4
    for (int i = wave; i < CH; i += 4) {
        float w = attn_s[i];
        float4 v = *(const float4*)(base + (size_t)i * HH);
        acc.x += w * v.x; acc.y += w * v.y; acc.z += w * v.z; acc.w += w * v.w;
    }
    *(float4*)(&red[wave][lane * 4]) = acc;
    __syncthreads();

    part[(size_t)(chunk * BB + b) * HH + t] =
        red[0][t] + red[1][t] + red[2][t] + red[3][t];
}

// ---------------------------------------------------------------------------
// Reduce partials -> context; Dc[b,j] = dec_W[j,256:512]·context[b] (bf16 W).
// grid = B, 256 threads.
// ---------------------------------------------------------------------------
__global__ __launch_bounds__(256) void k_ctx_red(
    const float* __restrict__ part, const u16* __restrict__ decWb,
    float* __restrict__ Dc)
{
    const int b = blockIdx.x, t = threadIdx.x;
    __shared__ float ctx_s[HH];

    float s = 0.f;
#pragma unroll
    for (int c = 0; c < NCHUNK; ++c) s += part[(size_t)(c * BB + b) * HH + t];
    ctx_s[t] = s;
    __syncthreads();

#pragma unroll
    for (int rr = 0; rr < 2; ++rr) {
        int j = t + rr * 256;
        float a2 = 0.f;
        const short8* p = (const short8*)(decWb + (size_t)j * H2 + HH);
#pragma unroll 4
        for (int cc = 0; cc < HH / 8; ++cc) {
            short8 w = p[cc];
#pragma unroll
            for (int k = 0; k < 8; ++k) a2 += bf2f((u16)w[k]) * ctx_s[cc * 8 + k];
        }
        Dc[b * H2 + j] = a2;
    }
}

// ---------------------------------------------------------------------------
extern "C" void kernel_launch(void* const* d_in, const int* in_sizes, int n_in,
                              void* d_out, int out_size, void* d_ws, size_t ws_size,
                              hipStream_t stream)
{
    const float* dec   = (const float*)d_in[0];
    const float* h0    = (const float*)d_in[1];
    const float* stat  = (const float*)d_in[2];
    const float* dyn   = (const float*)d_in[3];
    const float* embW  = (const float*)d_in[4];
    const float* embb  = (const float*)d_in[5];
    const float* Wih   = (const float*)d_in[6];
    const float* Whh   = (const float*)d_in[7];
    const float* bih   = (const float*)d_in[8];
    const float* bhh   = (const float*)d_in[9];
    const float* attnW = (const float*)d_in[10];
    const float* attnv = (const float*)d_in[11];
    const float* decW  = (const float*)d_in[12];
    const float* decv  = (const float*)d_in[13];

    float* out        = (float*)d_out;
    float* out_probs  = out;                 // [B, S]
    float* out_hidden = out + BB * SS;       // [1, B, H]

    u16* wsb     = (u16*)d_ws;
    u16* attnWb  = wsb;                      // 768*768 = 589824 u16
    u16* decWb   = wsb + 589824;             // 512*512 = 262144 u16
    float* wsf   = (float*)(wsb + 851968);
    float* Wh      = wsf;                    // B*768   =  98304
    float* scores  = wsf + 98304;            // B*S     = 128000
    float* attn    = wsf + 226304;           // B*S     = 128000
    float* Dc      = wsf + 354304;           // B*512   =  65536
    float* oscores = wsf + 419840;           // B*S     = 128000
    float* ctxpart = wsf + 547840;           // 8*B*256 = 262144

    k_prep<<<832, 256, 0, stream>>>(attnW, decW, attnWb, decWb);
    k_gru<<<BB, 256, 0, stream>>>(dec, h0, embW, embb, Wih, Whh, bih, bhh,
                                  attnW, Wh, out_hidden);
    k_scores<16, 48, H3, 2, 3><<<dim3(8, BB), 256, 0, stream>>>(stat, dyn, attnWb, Wh,
                                                                attnv, scores);
    k_softmax<<<BB, 256, 0, stream>>>(scores, attn);
    k_ctx_part<<<dim3(NCHUNK, BB), 256, 0, stream>>>(attn, stat, ctxpart);
    k_ctx_red<<<BB, 256, 0, stream>>>(ctxpart, decWb, Dc);
    k_scores<8, 32, H2, 1, 4><<<dim3(8, BB), 256, 0, stream>>>(stat, nullptr, decWb, Dc,
                                                               decv, oscores);
    k_softmax<<<BB, 256, 0, stream>>>(oscores, out_probs);
}

// Round 4
// 739.357 us; speedup vs baseline: 1.0471x; 1.0471x over previous
//
#include <hip/hip_runtime.h>

#define BB 128
#define SS 1000
#define HH 256
#define H3 768
#define H2 512
#define NCHUNK 8

typedef unsigned short u16;
typedef short short8 __attribute__((ext_vector_type(8)));
typedef float floatx4 __attribute__((ext_vector_type(4)));
typedef u16 ushort4v __attribute__((ext_vector_type(4)));

__device__ __forceinline__ float bf2f(u16 u) {
    union { unsigned int i; float f; } v;
    v.i = ((unsigned int)u) << 16;
    return v.f;
}

__device__ __forceinline__ u16 f2bf(float f) {
    unsigned int x = __float_as_uint(f);
    x += 0x7FFFu + ((x >> 16) & 1u);   // round-to-nearest-even
    return (u16)(x >> 16);
}

// tanh via one v_exp + one v_rcp; exact saturation at +-inf.
__device__ __forceinline__ float fast_tanh(float x) {
    float t = __expf(2.0f * x);
    return 1.0f - 2.0f * __builtin_amdgcn_rcpf(t + 1.0f);
}

__device__ __forceinline__ float sigmoidf(float x) {
    return __builtin_amdgcn_rcpf(1.0f + __expf(-x));
}

// ---------------------------------------------------------------------------
// Pre-pack attn_W (768 j x 512 k) and dec_W (512 j x 256 k) f32 -> bf16 in
// MFMA-fragment order: chunk index (g*KSTEPS + ks)*2 + jt, 512 u16 per chunk,
// u16 [lane*8 + e] = W[g*32 + jt*16 + (lane&15)][ks*32 + (lane>>4)*8 + e].
// A wave's B-fragment load is then ONE coalesced 16B/lane dwordx4 — no LDS,
// no swizzle, no barriers in the consumer.
// ---------------------------------------------------------------------------
__global__ __launch_bounds__(256) void k_prep(
    const float* __restrict__ aW, const float* __restrict__ dW,
    u16* __restrict__ aWp, u16* __restrict__ dWp)
{
    int idx = blockIdx.x * 256 + threadIdx.x;   // 65536 threads total
    const float* src;
    u16* dst;
    if (idx < 49152) {                          // attn_W: 24 g x 16 ks x 2 jt x 64
        int lane = idx & 63, chunk = idx >> 6;
        int jt = chunk & 1, t2 = chunk >> 1;
        int ks = t2 & 15, g = t2 >> 4;
        int c = lane & 15, q = lane >> 4;
        int j = g * 32 + jt * 16 + c;
        int k = ks * 32 + q * 8;
        src = aW + (size_t)j * H3 + k;
        dst = aWp + (size_t)idx * 8;
    } else {                                    // dec_W: 16 g x 8 ks x 2 jt x 64
        int i2 = idx - 49152;
        int lane = i2 & 63, chunk = i2 >> 6;
        int jt = chunk & 1, t2 = chunk >> 1;
        int ks = t2 & 7, g = t2 >> 3;
        int c = lane & 15, q = lane >> 4;
        int j = g * 32 + jt * 16 + c;
        int k = ks * 32 + q * 8;
        src = dW + (size_t)j * H2 + k;
        dst = dWp + (size_t)i2 * 8;
    }
    float4 u0 = *(const float4*)src;
    float4 u1 = *(const float4*)(src + 4);
    ushort4v o0 = { f2bf(u0.x), f2bf(u0.y), f2bf(u0.z), f2bf(u0.w) };
    ushort4v o1 = { f2bf(u1.x), f2bf(u1.y), f2bf(u1.z), f2bf(u1.w) };
    *(ushort4v*)dst = o0;
    *(ushort4v*)(dst + 4) = o1;
}

// ---------------------------------------------------------------------------
// embed + GRU cell + hidden out + Wh[b,j] = attn_W[j,512:768]·h_new[b]
// ---------------------------------------------------------------------------
__global__ __launch_bounds__(256) void k_gru(
    const float* __restrict__ dec, const float* __restrict__ h0,
    const float* __restrict__ embW, const float* __restrict__ embb,
    const float* __restrict__ Wih, const float* __restrict__ Whh,
    const float* __restrict__ bih, const float* __restrict__ bhh,
    const float* __restrict__ attnW,
    float* __restrict__ Wh, float* __restrict__ out_hidden)
{
    const int b = blockIdx.x, t = threadIdx.x;
    __shared__ float emb_s[HH], h_s[HH], hn_s[HH];

    const float d0 = dec[b * 2 + 0], d1 = dec[b * 2 + 1];
    emb_s[t] = d0 * embW[t * 2 + 0] + d1 * embW[t * 2 + 1] + embb[t];
    h_s[t] = h0[b * HH + t];
    __syncthreads();

    auto dotrow = [&](const float* Wr, const float* xs) -> float {
        float acc = 0.f;
        const float4* p = (const float4*)Wr;
#pragma unroll 8
        for (int c = 0; c < HH / 4; ++c) {
            float4 w = p[c];
            acc += w.x * xs[c * 4 + 0] + w.y * xs[c * 4 + 1]
                 + w.z * xs[c * 4 + 2] + w.w * xs[c * 4 + 3];
        }
        return acc;
    };

    float gr = dotrow(Wih + (size_t)t * HH, emb_s) + bih[t]
             + dotrow(Whh + (size_t)t * HH, h_s) + bhh[t];
    float r = sigmoidf(gr);

    float gz = dotrow(Wih + (size_t)(HH + t) * HH, emb_s) + bih[HH + t]
             + dotrow(Whh + (size_t)(HH + t) * HH, h_s) + bhh[HH + t];
    float z = sigmoidf(gz);

    float xn = dotrow(Wih + (size_t)(2 * HH + t) * HH, emb_s) + bih[2 * HH + t];
    float hn = dotrow(Whh + (size_t)(2 * HH + t) * HH, h_s) + bhh[2 * HH + t];
    float n = fast_tanh(xn + r * hn);

    float hv = (1.0f - z) * n + z * h_s[t];
    out_hidden[b * HH + t] = hv;
    hn_s[t] = hv;
    __syncthreads();

#pragma unroll
    for (int rr = 0; rr < 3; ++rr) {
        int j = t + rr * HH;
        Wh[b * H3 + j] = dotrow(attnW + (size_t)j * H3 + 2 * HH, hn_s);
    }
}

// ---------------------------------------------------------------------------
// Score GEMM: out[b,s] = sum_j vj[j] * tanh( (A @ W^T)[s,j] + addj[b,j] )
// A held full-K in regs (spill-free only at 2 waves/SIMD for KSTEPS=16 —
// rounds 1&3 proved MINW=3 spills with the 128-reg afrag; do not retry).
// W is streamed DIRECTLY FROM GLOBAL in pre-packed fragment order: one
// coalesced dwordx4 per B-fragment, L2-resident, no LDS, no __syncthreads
// in the loop, no bank conflicts — the compiler software-pipelines the
// loads against MFMA with the ~80 spare VGPRs.
// grid = (8, B); block = 256 = 4 waves; wave = 2 m-tiles of 16 s-rows.
// ---------------------------------------------------------------------------
template <int KSTEPS, int NTILES, int MINW>
__global__ __launch_bounds__(256, MINW) void k_scores(
    const float* __restrict__ A1, const float* __restrict__ A2,
    const u16* __restrict__ Wp, const float* __restrict__ addj,
    const float* __restrict__ vj, float* __restrict__ out)
{
    constexpr int NG = NTILES / 2;         // groups of 32 j-rows
    constexpr int NJ = NTILES * 16;        // total j

    __shared__ float aj_s[NJ], vj_s[NJ];

    const int b = blockIdx.y, t = threadIdx.x;
    const int wave = t >> 6, lane = t & 63;
    const int q = lane >> 4, c = lane & 15;
    const int s_base = blockIdx.x * 128 + wave * 32;
    const int kb = q * 8;

    // ---- preload addj row + v into LDS -----------------------------------
    for (int i = t; i < NJ; i += 256) {
        aj_s[i] = addj[b * NJ + i];
        vj_s[i] = vj[i];
    }

    // ---- A fragments, full K, in registers -------------------------------
    short8 afrag[2][KSTEPS];
#pragma unroll
    for (int mt = 0; mt < 2; ++mt) {
        int row = s_base + mt * 16 + c;
        if (row > SS - 1) row = SS - 1;            // tail clamp; writes guarded
        const size_t abase = (size_t)(b * SS + row) * HH;
#pragma unroll
        for (int ks = 0; ks < KSTEPS; ++ks) {
            int k = ks * 32 + kb;
            const float* src;
            if constexpr (KSTEPS * 32 <= HH) {
                src = A1 + abase + k;
            } else {
                src = (k < HH) ? (A1 + abase + k) : (A2 + abase + (k - HH));
            }
            float4 u0 = *(const float4*)src;
            float4 u1 = *(const float4*)(src + 4);
            short8 f;
            f[0] = (short)f2bf(u0.x); f[1] = (short)f2bf(u0.y);
            f[2] = (short)f2bf(u0.z); f[3] = (short)f2bf(u0.w);
            f[4] = (short)f2bf(u1.x); f[5] = (short)f2bf(u1.y);
            f[6] = (short)f2bf(u1.z); f[7] = (short)f2bf(u1.w);
            afrag[mt][ks] = f;
        }
    }

    __syncthreads();                        // aj_s/vj_s ready (only barrier)

    float pout[2][4] = {{0.f, 0.f, 0.f, 0.f}, {0.f, 0.f, 0.f, 0.f}};
    const u16* wpl = Wp + lane * 8;         // this lane's slot in each chunk

    for (int g = 0; g < NG; ++g) {
        floatx4 acc[2][2];                  // [jt][mt]
#pragma unroll
        for (int jt = 0; jt < 2; ++jt)
#pragma unroll
            for (int mt = 0; mt < 2; ++mt)
                acc[jt][mt] = (floatx4){0.f, 0.f, 0.f, 0.f};

        const u16* gb = wpl + (size_t)g * (KSTEPS * 1024);
#pragma unroll
        for (int ks = 0; ks < KSTEPS; ++ks) {
            short8 wf0 = *(const short8*)(gb + ks * 1024);
            short8 wf1 = *(const short8*)(gb + ks * 1024 + 512);
            acc[0][0] = __builtin_amdgcn_mfma_f32_16x16x32_bf16(afrag[0][ks], wf0, acc[0][0], 0, 0, 0);
            acc[0][1] = __builtin_amdgcn_mfma_f32_16x16x32_bf16(afrag[1][ks], wf0, acc[0][1], 0, 0, 0);
            acc[1][0] = __builtin_amdgcn_mfma_f32_16x16x32_bf16(afrag[0][ks], wf1, acc[1][0], 0, 0, 0);
            acc[1][1] = __builtin_amdgcn_mfma_f32_16x16x32_bf16(afrag[1][ks], wf1, acc[1][1], 0, 0, 0);
        }

        // inline epilogue (VALU) — overlaps with next group's W loads
#pragma unroll
        for (int jt = 0; jt < 2; ++jt) {
            const int j = g * 32 + jt * 16 + c;
            const float aj = aj_s[j];
            const float vv = vj_s[j];
#pragma unroll
            for (int r4 = 0; r4 < 4; ++r4) {
                pout[0][r4] += fast_tanh(acc[jt][0][r4] + aj) * vv;
                pout[1][r4] += fast_tanh(acc[jt][1][r4] + aj) * vv;
            }
        }
    }

    // reduce over the 16 lanes of each quad (the j-columns)
#pragma unroll
    for (int mt = 0; mt < 2; ++mt)
#pragma unroll
        for (int r4 = 0; r4 < 4; ++r4)
#pragma unroll
            for (int off = 1; off < 16; off <<= 1)
                pout[mt][r4] += __shfl_xor(pout[mt][r4], off, 64);

    if (c == 0) {
#pragma unroll
        for (int mt = 0; mt < 2; ++mt) {
            const int srow = s_base + mt * 16 + q * 4;
#pragma unroll
            for (int r4 = 0; r4 < 4; ++r4)
                if (srow + r4 < SS) out[b * SS + srow + r4] = pout[mt][r4];
        }
    }
}

// ---------------------------------------------------------------------------
// Softmax over S per batch row; f32 in, f32 out.
// ---------------------------------------------------------------------------
__global__ __launch_bounds__(256) void k_softmax(
    const float* __restrict__ in, float* __restrict__ outf)
{
    const int b = blockIdx.x, t = threadIdx.x;
    __shared__ float red[4];
    const float* rowp = in + b * SS;

    float m = -1e30f;
    for (int s = t; s < SS; s += 256) m = fmaxf(m, rowp[s]);
#pragma unroll
    for (int off = 32; off >= 1; off >>= 1) m = fmaxf(m, __shfl_xor(m, off, 64));
    if ((t & 63) == 0) red[t >> 6] = m;
    __syncthreads();
    m = fmaxf(fmaxf(red[0], red[1]), fmaxf(red[2], red[3]));

    float sum = 0.f;
    for (int s = t; s < SS; s += 256) sum += __expf(rowp[s] - m);
#pragma unroll
    for (int off = 32; off >= 1; off >>= 1) sum += __shfl_xor(sum, off, 64);
    __syncthreads();
    if ((t & 63) == 0) red[t >> 6] = sum;
    __syncthreads();
    sum = red[0] + red[1] + red[2] + red[3];

    const float inv = 1.0f / sum;
    for (int s = t; s < SS; s += 256)
        outf[b * SS + s] = __expf(rowp[s] - m) * inv;
}

// ---------------------------------------------------------------------------
// Context partials: chunk of 125 s-rows per block; wave-per-row float4 loads.
// part[chunk][b][h] = sum_{s in chunk} attn[b,s] * static[b,s,h]
// grid = (NCHUNK, B), 256 threads.
// ---------------------------------------------------------------------------
__global__ __launch_bounds__(256) void k_ctx_part(
    const float* __restrict__ attn, const float* __restrict__ stat,
    float* __restrict__ part)
{
    constexpr int CH = SS / NCHUNK;            // 125
    const int chunk = blockIdx.x, b = blockIdx.y, t = threadIdx.x;
    const int wave = t >> 6, lane = t & 63;

    __shared__ float attn_s[CH];
    __shared__ float red[4][HH];

    for (int i = t; i < CH; i += 256) attn_s[i] = attn[b * SS + chunk * CH + i];
    __syncthreads();

    float4 acc = {0.f, 0.f, 0.f, 0.f};
    const float* base = stat + ((size_t)(b * SS + chunk * CH) * HH) + lane * 4;
#pragma unroll 4
    for (int i = wave; i < CH; i += 4) {
        float w = attn_s[i];
        float4 v = *(const float4*)(base + (size_t)i * HH);
        acc.x += w * v.x; acc.y += w * v.y; acc.z += w * v.z; acc.w += w * v.w;
    }
    *(float4*)(&red[wave][lane * 4]) = acc;
    __syncthreads();

    part[(size_t)(chunk * BB + b) * HH + t] =
        red[0][t] + red[1][t] + red[2][t] + red[3][t];
}

// ---------------------------------------------------------------------------
// Reduce partials -> context; Dc[b,j] = dec_W[j,256:512]·context[b].
// grid = B, 256 threads. (reads original f32 dec_W — packed buffer only
// holds the k<256 half used by the GEMM)
// ---------------------------------------------------------------------------
__global__ __launch_bounds__(256) void k_ctx_red(
    const float* __restrict__ part, const float* __restrict__ decW,
    float* __restrict__ Dc)
{
    const int b = blockIdx.x, t = threadIdx.x;
    __shared__ float ctx_s[HH];

    float s = 0.f;
#pragma unroll
    for (int c = 0; c < NCHUNK; ++c) s += part[(size_t)(c * BB + b) * HH + t];
    ctx_s[t] = s;
    __syncthreads();

#pragma unroll
    for (int rr = 0; rr < 2; ++rr) {
        int j = t + rr * 256;
        float a2 = 0.f;
        const float4* p = (const float4*)(decW + (size_t)j * H2 + HH);
#pragma unroll 4
        for (int cc = 0; cc < HH / 4; ++cc) {
            float4 w = p[cc];
            a2 += w.x * ctx_s[cc * 4 + 0] + w.y * ctx_s[cc * 4 + 1]
                + w.z * ctx_s[cc * 4 + 2] + w.w * ctx_s[cc * 4 + 3];
        }
        Dc[b * H2 + j] = a2;
    }
}

// ---------------------------------------------------------------------------
extern "C" void kernel_launch(void* const* d_in, const int* in_sizes, int n_in,
                              void* d_out, int out_size, void* d_ws, size_t ws_size,
                              hipStream_t stream)
{
    const float* dec   = (const float*)d_in[0];
    const float* h0    = (const float*)d_in[1];
    const float* stat  = (const float*)d_in[2];
    const float* dyn   = (const float*)d_in[3];
    const float* embW  = (const float*)d_in[4];
    const float* embb  = (const float*)d_in[5];
    const float* Wih   = (const float*)d_in[6];
    const float* Whh   = (const float*)d_in[7];
    const float* bih   = (const float*)d_in[8];
    const float* bhh   = (const float*)d_in[9];
    const float* attnW = (const float*)d_in[10];
    const float* attnv = (const float*)d_in[11];
    const float* decW  = (const float*)d_in[12];
    const float* decv  = (const float*)d_in[13];

    float* out        = (float*)d_out;
    float* out_probs  = out;                 // [B, S]
    float* out_hidden = out + BB * SS;       // [1, B, H]

    u16* wsb     = (u16*)d_ws;
    u16* attnWp  = wsb;                      // 768*512 = 393216 u16 (packed)
    u16* decWp   = wsb + 393216;             // 512*256 = 131072 u16 (packed)
    float* wsf   = (float*)(wsb + 851968);   // offsets unchanged
    float* Wh      = wsf;                    // B*768   =  98304
    float* scores  = wsf + 98304;            // B*S     = 128000
    float* attn    = wsf + 226304;           // B*S     = 128000
    float* Dc      = wsf + 354304;           // B*512   =  65536
    float* oscores = wsf + 419840;           // B*S     = 128000
    float* ctxpart = wsf + 547840;           // 8*B*256 = 262144

    k_prep<<<256, 256, 0, stream>>>(attnW, decW, attnWp, decWp);
    k_gru<<<BB, 256, 0, stream>>>(dec, h0, embW, embb, Wih, Whh, bih, bhh,
                                  attnW, Wh, out_hidden);
    k_scores<16, 48, 2><<<dim3(8, BB), 256, 0, stream>>>(stat, dyn, attnWp, Wh,
                                                         attnv, scores);
    k_softmax<<<BB, 256, 0, stream>>>(scores, attn);
    k_ctx_part<<<dim3(NCHUNK, BB), 256, 0, stream>>>(attn, stat, ctxpart);
    k_ctx_red<<<BB, 256, 0, stream>>>(ctxpart, decW, Dc);
    k_scores<8, 32, 3><<<dim3(8, BB), 256, 0, stream>>>(stat, nullptr, decWp, Dc,
                                                        decv, oscores);
    k_softmax<<<BB, 256, 0, stream>>>(oscores, out_probs);
}

// Round 5
// 601.315 us; speedup vs baseline: 1.2875x; 1.2296x over previous
//
#include <hip/hip_runtime.h>

#define BB 128
#define SS 1000
#define HH 256
#define H3 768
#define H2 512
#define NCHUNK 8

typedef unsigned short u16;
typedef short short8 __attribute__((ext_vector_type(8)));
typedef float floatx4 __attribute__((ext_vector_type(4)));
typedef u16 ushort4v __attribute__((ext_vector_type(4)));

__device__ __forceinline__ float bf2f(u16 u) {
    union { unsigned int i; float f; } v;
    v.i = ((unsigned int)u) << 16;
    return v.f;
}

__device__ __forceinline__ u16 f2bf(float f) {
    unsigned int x = __float_as_uint(f);
    x += 0x7FFFu + ((x >> 16) & 1u);   // round-to-nearest-even
    return (u16)(x >> 16);
}

// tanh via one v_exp + one v_rcp; exact saturation at +-inf.
__device__ __forceinline__ float fast_tanh(float x) {
    float t = __expf(2.0f * x);
    return 1.0f - 2.0f * __builtin_amdgcn_rcpf(t + 1.0f);
}

__device__ __forceinline__ float sigmoidf(float x) {
    return __builtin_amdgcn_rcpf(1.0f + __expf(-x));
}

// async 16B global -> LDS (dest = wave-uniform base + lane*16)
__device__ __forceinline__ void gl2lds16(const void* src, void* dst) {
    __builtin_amdgcn_global_load_lds(
        (const __attribute__((address_space(1))) unsigned int*)src,
        (__attribute__((address_space(3))) unsigned int*)dst,
        16, 0, 0);
}

// ---------------------------------------------------------------------------
// Pre-convert attn_W [768x768] and dec_W [512x512] f32 -> bf16 in workspace.
// ---------------------------------------------------------------------------
__global__ __launch_bounds__(256) void k_prep(
    const float* __restrict__ aW, const float* __restrict__ dW,
    u16* __restrict__ aWb, u16* __restrict__ dWb)
{
    int idx = (blockIdx.x * 256 + threadIdx.x) * 4;
    const float* src;
    u16* dst;
    if (idx < 589824) { src = aW + idx; dst = aWb + idx; }
    else              { src = dW + (idx - 589824); dst = dWb + (idx - 589824); }
    float4 v = *(const float4*)src;
    ushort4v o = { f2bf(v.x), f2bf(v.y), f2bf(v.z), f2bf(v.w) };
    *(ushort4v*)dst = o;
}

// ---------------------------------------------------------------------------
// embed + GRU cell + hidden out + Wh[b,j] = attn_W[j,512:768]·h_new[b]
// ---------------------------------------------------------------------------
__global__ __launch_bounds__(256) void k_gru(
    const float* __restrict__ dec, const float* __restrict__ h0,
    const float* __restrict__ embW, const float* __restrict__ embb,
    const float* __restrict__ Wih, const float* __restrict__ Whh,
    const float* __restrict__ bih, const float* __restrict__ bhh,
    const float* __restrict__ attnW,
    float* __restrict__ Wh, float* __restrict__ out_hidden)
{
    const int b = blockIdx.x, t = threadIdx.x;
    __shared__ float emb_s[HH], h_s[HH], hn_s[HH];

    const float d0 = dec[b * 2 + 0], d1 = dec[b * 2 + 1];
    emb_s[t] = d0 * embW[t * 2 + 0] + d1 * embW[t * 2 + 1] + embb[t];
    h_s[t] = h0[b * HH + t];
    __syncthreads();

    auto dotrow = [&](const float* Wr, const float* xs) -> float {
        float acc = 0.f;
        const float4* p = (const float4*)Wr;
#pragma unroll 8
        for (int c = 0; c < HH / 4; ++c) {
            float4 w = p[c];
            acc += w.x * xs[c * 4 + 0] + w.y * xs[c * 4 + 1]
                 + w.z * xs[c * 4 + 2] + w.w * xs[c * 4 + 3];
        }
        return acc;
    };

    float gr = dotrow(Wih + (size_t)t * HH, emb_s) + bih[t]
             + dotrow(Whh + (size_t)t * HH, h_s) + bhh[t];
    float r = sigmoidf(gr);

    float gz = dotrow(Wih + (size_t)(HH + t) * HH, emb_s) + bih[HH + t]
             + dotrow(Whh + (size_t)(HH + t) * HH, h_s) + bhh[HH + t];
    float z = sigmoidf(gz);

    float xn = dotrow(Wih + (size_t)(2 * HH + t) * HH, emb_s) + bih[2 * HH + t];
    float hn = dotrow(Whh + (size_t)(2 * HH + t) * HH, h_s) + bhh[2 * HH + t];
    float n = fast_tanh(xn + r * hn);

    float hv = (1.0f - z) * n + z * h_s[t];
    out_hidden[b * HH + t] = hv;
    hn_s[t] = hv;
    __syncthreads();

#pragma unroll
    for (int rr = 0; rr < 3; ++rr) {
        int j = t + rr * HH;
        Wh[b * H3 + j] = dotrow(attnW + (size_t)j * H3 + 2 * HH, hn_s);
    }
}

// ---------------------------------------------------------------------------
// Score GEMM: out[b,s] = sum_j vj[j] * tanh( (A @ Wb^T)[s,j] + addj[b,j] )
// A held full-K in regs (VGPR=128; MINW>2 with KSTEPS=16 spills — settled,
// rounds 1&3). W staged via global_load_lds with XOR swizzle into a
// 3-buffer, prefetch-distance-2 pipeline with COUNTED vmcnt + raw barrier
// (m201/m218 pattern): the drain-to-zero at __syncthreads was the dominant
// stall (rounds 0-4: no pipe >26% busy). Invariant per unit u: outstanding
// <= {stage(u), stage(u+1)} = 8 loads/wave; s_waitcnt vmcnt(4) completes
// stage(u) (vmcnt retires in issue order); barrier publishes it; stage(u+2)
// then reuses the buffer last read at u-1, ordered by the same barrier.
// grid = (8, B); block = 256 = 4 waves; wave = 2 m-tiles of 16 s-rows.
// ---------------------------------------------------------------------------
template <int KSTEPS, int NTILES, int WSTRIDE, int HALVES, int MINW>
__global__ __launch_bounds__(256, MINW) void k_scores(
    const float* __restrict__ A1, const float* __restrict__ A2,
    const u16* __restrict__ Wb, const float* __restrict__ addj,
    const float* __restrict__ vj, float* __restrict__ out)
{
    constexpr int GPR    = KSTEPS * 4;       // 16B granules per j-row (full K)
    constexpr int KH     = KSTEPS / HALVES;  // k-steps per staged unit
    constexpr int GPH    = GPR / HALVES;     // granules per row per unit
    constexpr int BUFU16 = 32 * GPH * 8;     // u16 per buffer (32 rows)
    constexpr int NINSTR = BUFU16 / 2048;    // global_load_lds per wave per stage
    constexpr int NG     = NTILES / 2;       // groups of 32 j-rows
    constexpr int NU     = NG * HALVES;      // total stage units
    constexpr int NJ     = NTILES * 16;      // total j

    static_assert(NINSTR == 4, "vmcnt literal below assumes 4 loads/wave/stage");

    __shared__ u16 smem[3 * BUFU16];         // 3 buffers: prefetch distance 2
    __shared__ float aj_s[NJ], vj_s[NJ];

    const int b = blockIdx.y, t = threadIdx.x;
    const int wave = t >> 6, lane = t & 63;
    const int q = lane >> 4, c = lane & 15;
    const int swz = c & 7;
    const int s_base = blockIdx.x * 128 + wave * 32;
    const int kb = q * 8;

    // ---- stage unit u = g*HALVES + h into buffer sel ---------------------
    auto stage = [&](int u, int sel) {
        const int g = u / HALVES, h = u % HALVES;
        const int jbase = g * 32;
        u16* base = smem + sel * BUFU16;
#pragma unroll
        for (int i = 0; i < NINSTR; ++i) {
            int gl = (wave * NINSTR + i) * 64 + lane;   // granule index in buffer
            int r  = gl / GPH;                          // local j-row 0..31
            int p  = gl % GPH;                          // physical granule in row
            int gg = p ^ (r & 7);                       // logical (source) granule
            const u16* src = Wb + (size_t)(jbase + r) * WSTRIDE
                           + h * (GPH * 8) + gg * 8;
            u16* dst = base + (wave * NINSTR + i) * 512;  // uniform/wave
            gl2lds16(src, dst);
        }
    };
    stage(0, 0);
    if (NU > 1) stage(1, 1);

    // ---- preload addj row + v into LDS -----------------------------------
    for (int i = t; i < NJ; i += 256) {
        aj_s[i] = addj[b * NJ + i];
        vj_s[i] = vj[i];
    }

    // ---- A fragments, full K, in registers -------------------------------
    short8 afrag[2][KSTEPS];
#pragma unroll
    for (int mt = 0; mt < 2; ++mt) {
        int row = s_base + mt * 16 + c;
        if (row > SS - 1) row = SS - 1;            // tail clamp; writes guarded
        const size_t abase = (size_t)(b * SS + row) * HH;
#pragma unroll
        for (int ks = 0; ks < KSTEPS; ++ks) {
            int k = ks * 32 + kb;
            const float* src;
            if constexpr (KSTEPS * 32 <= HH) {
                src = A1 + abase + k;
            } else {
                src = (k < HH) ? (A1 + abase + k) : (A2 + abase + (k - HH));
            }
            float4 u0 = *(const float4*)src;
            float4 u1 = *(const float4*)(src + 4);
            short8 f;
            f[0] = (short)f2bf(u0.x); f[1] = (short)f2bf(u0.y);
            f[2] = (short)f2bf(u0.z); f[3] = (short)f2bf(u0.w);
            f[4] = (short)f2bf(u1.x); f[5] = (short)f2bf(u1.y);
            f[6] = (short)f2bf(u1.z); f[7] = (short)f2bf(u1.w);
            afrag[mt][ks] = f;
        }
    }

    __syncthreads();   // one-time full drain: stage(0),(1) landed; aj/vj ready

    float pout[2][4] = {{0.f, 0.f, 0.f, 0.f}, {0.f, 0.f, 0.f, 0.f}};

    for (int g = 0; g < NG; ++g) {
        floatx4 acc[2][2];                    // [jt][mt]
#pragma unroll
        for (int jt = 0; jt < 2; ++jt)
#pragma unroll
            for (int mt = 0; mt < 2; ++mt)
                acc[jt][mt] = (floatx4){0.f, 0.f, 0.f, 0.f};

#pragma unroll
        for (int h = 0; h < HALVES; ++h) {
            const int u = g * HALVES + h;
            const int sel = u % 3;

            // counted wait: allow the newest stage (4 loads) to stay in
            // flight; guarantees stage(u) (2 iterations old) has landed.
            asm volatile("s_waitcnt vmcnt(4)");
            __builtin_amdgcn_sched_barrier(0);
            __builtin_amdgcn_s_barrier();
            __builtin_amdgcn_sched_barrier(0);

            if (u + 2 < NU) stage(u + 2, (u + 2) % 3);

            const u16* base = smem + sel * BUFU16;

            auto ldsrd = [&](int ks, int jt) -> short8 {
                const int paddr = ((jt * 16 + c) * GPH + ((ks * 4 + q) ^ swz)) * 8;
                return *(const short8*)(base + paddr);
            };

            __builtin_amdgcn_s_setprio(1);
#pragma unroll
            for (int ks = 0; ks < KH; ++ks) {
                short8 wf0 = ldsrd(ks, 0);
                short8 wf1 = ldsrd(ks, 1);
                acc[0][0] = __builtin_amdgcn_mfma_f32_16x16x32_bf16(afrag[0][h * KH + ks], wf0, acc[0][0], 0, 0, 0);
                acc[0][1] = __builtin_amdgcn_mfma_f32_16x16x32_bf16(afrag[1][h * KH + ks], wf0, acc[0][1], 0, 0, 0);
                acc[1][0] = __builtin_amdgcn_mfma_f32_16x16x32_bf16(afrag[0][h * KH + ks], wf1, acc[1][0], 0, 0, 0);
                acc[1][1] = __builtin_amdgcn_mfma_f32_16x16x32_bf16(afrag[1][h * KH + ks], wf1, acc[1][1], 0, 0, 0);
            }
            __builtin_amdgcn_s_setprio(0);
        }

        // inline epilogue (VALU) — overlaps other waves' MFMA via scheduler
#pragma unroll
        for (int jt = 0; jt < 2; ++jt) {
            const int j = g * 32 + jt * 16 + c;
            const float aj = aj_s[j];
            const float vv = vj_s[j];
#pragma unroll
            for (int r4 = 0; r4 < 4; ++r4) {
                pout[0][r4] += fast_tanh(acc[jt][0][r4] + aj) * vv;
                pout[1][r4] += fast_tanh(acc[jt][1][r4] + aj) * vv;
            }
        }
    }

    // reduce over the 16 lanes of each quad (the j-columns)
#pragma unroll
    for (int mt = 0; mt < 2; ++mt)
#pragma unroll
        for (int r4 = 0; r4 < 4; ++r4)
#pragma unroll
            for (int off = 1; off < 16; off <<= 1)
                pout[mt][r4] += __shfl_xor(pout[mt][r4], off, 64);

    if (c == 0) {
#pragma unroll
        for (int mt = 0; mt < 2; ++mt) {
            const int srow = s_base + mt * 16 + q * 4;
#pragma unroll
            for (int r4 = 0; r4 < 4; ++r4)
                if (srow + r4 < SS) out[b * SS + srow + r4] = pout[mt][r4];
        }
    }
}

// ---------------------------------------------------------------------------
// Softmax over S per batch row; f32 in, f32 out.
// ---------------------------------------------------------------------------
__global__ __launch_bounds__(256) void k_softmax(
    const float* __restrict__ in, float* __restrict__ outf)
{
    const int b = blockIdx.x, t = threadIdx.x;
    __shared__ float red[4];
    const float* rowp = in + b * SS;

    float m = -1e30f;
    for (int s = t; s < SS; s += 256) m = fmaxf(m, rowp[s]);
#pragma unroll
    for (int off = 32; off >= 1; off >>= 1) m = fmaxf(m, __shfl_xor(m, off, 64));
    if ((t & 63) == 0) red[t >> 6] = m;
    __syncthreads();
    m = fmaxf(fmaxf(red[0], red[1]), fmaxf(red[2], red[3]));

    float sum = 0.f;
    for (int s = t; s < SS; s += 256) sum += __expf(rowp[s] - m);
#pragma unroll
    for (int off = 32; off >= 1; off >>= 1) sum += __shfl_xor(sum, off, 64);
    __syncthreads();
    if ((t & 63) == 0) red[t >> 6] = sum;
    __syncthreads();
    sum = red[0] + red[1] + red[2] + red[3];

    const float inv = 1.0f / sum;
    for (int s = t; s < SS; s += 256)
        outf[b * SS + s] = __expf(rowp[s] - m) * inv;
}

// ---------------------------------------------------------------------------
// Context partials: chunk of 125 s-rows per block; wave-per-row float4 loads.
// part[chunk][b][h] = sum_{s in chunk} attn[b,s] * static[b,s,h]
// grid = (NCHUNK, B), 256 threads.
// ---------------------------------------------------------------------------
__global__ __launch_bounds__(256) void k_ctx_part(
    const float* __restrict__ attn, const float* __restrict__ stat,
    float* __restrict__ part)
{
    constexpr int CH = SS / NCHUNK;            // 125
    const int chunk = blockIdx.x, b = blockIdx.y, t = threadIdx.x;
    const int wave = t >> 6, lane = t & 63;

    __shared__ float attn_s[CH];
    __shared__ float red[4][HH];

    for (int i = t; i < CH; i += 256) attn_s[i] = attn[b * SS + chunk * CH + i];
    __syncthreads();

    float4 acc = {0.f, 0.f, 0.f, 0.f};
    const float* base = stat + ((size_t)(b * SS + chunk * CH) * HH) + lane * 4;
#pragma unroll 4
    for (int i = wave; i < CH; i += 4) {
        float w = attn_s[i];
        float4 v = *(const float4*)(base + (size_t)i * HH);
        acc.x += w * v.x; acc.y += w * v.y; acc.z += w * v.z; acc.w += w * v.w;
    }
    *(float4*)(&red[wave][lane * 4]) = acc;
    __syncthreads();

    part[(size_t)(chunk * BB + b) * HH + t] =
        red[0][t] + red[1][t] + red[2][t] + red[3][t];
}

// ---------------------------------------------------------------------------
// Reduce partials -> context; Dc[b,j] = dec_W[j,256:512]·context[b] (bf16 W).
// grid = B, 256 threads.
// ---------------------------------------------------------------------------
__global__ __launch_bounds__(256) void k_ctx_red(
    const float* __restrict__ part, const u16* __restrict__ decWb,
    float* __restrict__ Dc)
{
    const int b = blockIdx.x, t = threadIdx.x;
    __shared__ float ctx_s[HH];

    float s = 0.f;
#pragma unroll
    for (int c = 0; c < NCHUNK; ++c) s += part[(size_t)(c * BB + b) * HH + t];
    ctx_s[t] = s;
    __syncthreads();

#pragma unroll
    for (int rr = 0; rr < 2; ++rr) {
        int j = t + rr * 256;
        float a2 = 0.f;
        const short8* p = (const short8*)(decWb + (size_t)j * H2 + HH);
#pragma unroll 4
        for (int cc = 0; cc < HH / 8; ++cc) {
            short8 w = p[cc];
#pragma unroll
            for (int k = 0; k < 8; ++k) a2 += bf2f((u16)w[k]) * ctx_s[cc * 8 + k];
        }
        Dc[b * H2 + j] = a2;
    }
}

// ---------------------------------------------------------------------------
extern "C" void kernel_launch(void* const* d_in, const int* in_sizes, int n_in,
                              void* d_out, int out_size, void* d_ws, size_t ws_size,
                              hipStream_t stream)
{
    const float* dec   = (const float*)d_in[0];
    const float* h0    = (const float*)d_in[1];
    const float* stat  = (const float*)d_in[2];
    const float* dyn   = (const float*)d_in[3];
    const float* embW  = (const float*)d_in[4];
    const float* embb  = (const float*)d_in[5];
    const float* Wih   = (const float*)d_in[6];
    const float* Whh   = (const float*)d_in[7];
    const float* bih   = (const float*)d_in[8];
    const float* bhh   = (const float*)d_in[9];
    const float* attnW = (const float*)d_in[10];
    const float* attnv = (const float*)d_in[11];
    const float* decW  = (const float*)d_in[12];
    const float* decv  = (const float*)d_in[13];

    float* out        = (float*)d_out;
    float* out_probs  = out;                 // [B, S]
    float* out_hidden = out + BB * SS;       // [1, B, H]

    u16* wsb     = (u16*)d_ws;
    u16* attnWb  = wsb;                      // 768*768 = 589824 u16
    u16* decWb   = wsb + 589824;             // 512*512 = 262144 u16
    float* wsf   = (float*)(wsb + 851968);
    float* Wh      = wsf;                    // B*768   =  98304
    float* scores  = wsf + 98304;            // B*S     = 128000
    float* attn    = wsf + 226304;           // B*S     = 128000
    float* Dc      = wsf + 354304;           // B*512   =  65536
    float* oscores = wsf + 419840;           // B*S     = 128000
    float* ctxpart = wsf + 547840;           // 8*B*256 = 262144

    k_prep<<<832, 256, 0, stream>>>(attnW, decW, attnWb, decWb);
    k_gru<<<BB, 256, 0, stream>>>(dec, h0, embW, embb, Wih, Whh, bih, bhh,
                                  attnW, Wh, out_hidden);
    k_scores<16, 48, H3, 2, 2><<<dim3(8, BB), 256, 0, stream>>>(stat, dyn, attnWb, Wh,
                                                                attnv, scores);
    k_softmax<<<BB, 256, 0, stream>>>(scores, attn);
    k_ctx_part<<<dim3(NCHUNK, BB), 256, 0, stream>>>(attn, stat, ctxpart);
    k_ctx_red<<<BB, 256, 0, stream>>>(ctxpart, decWb, Dc);
    k_scores<8, 32, H2, 1, 3><<<dim3(8, BB), 256, 0, stream>>>(stat, nullptr, decWb, Dc,
                                                               decv, oscores);
    k_softmax<<<BB, 256, 0, stream>>>(oscores, out_probs);
}